// Round 1
// baseline (1337.379 us; speedup 1.0000x reference)
//
#include <hip/hip_runtime.h>
#include <hip/hip_bf16.h>
#include <math.h>

// Problem constants
constexpr int B  = 128;
constexpr int S  = 128;
constexpr int H  = 1024;
constexpr int E  = 512;
constexpr int V  = 32000;
constexpr int H2 = 2 * H;     // 2048
constexpr int G4 = 4 * H;     // 4096
constexpr int KX = E + H;     // 1536
constexpr int KG = KX + H;    // 2560
constexpr int BS = B * S;     // 16384

// ---------------------------------------------------------------------------
// Kernel 1: q[b,h] = attn_b[h] + dot(h_last[b,:], attn_W[h, 0:H])
// One thread per output; all lanes in a wave share b, consecutive h.
// attn_W[:, :H] is 4MB -> L2-resident, per-thread k-sequential float4 reads.
// ---------------------------------------------------------------------------
__global__ __launch_bounds__(256) void k_q(const float* __restrict__ hlast,
                                           const float* __restrict__ attn_W,
                                           const float* __restrict__ attn_b,
                                           float* __restrict__ q) {
    int idx = blockIdx.x * 256 + threadIdx.x;   // 512 blocks
    int b = idx >> 10;
    int h = idx & (H - 1);
    const float* arow = attn_W + (size_t)h * H2;   // first H cols = W1
    const float* hrow = hlast + (size_t)b * H;
    float acc = 0.f;
    for (int k = 0; k < H; k += 4) {
        float4 a = *(const float4*)(arow + k);
        float4 x = *(const float4*)(hrow + k);
        acc += a.x * x.x + a.y * x.y + a.z * x.z + a.w * x.w;
    }
    q[idx] = acc + attn_b[h];
}

// ---------------------------------------------------------------------------
// Kernel 2: energy GEMM + fused tanh + dot-with-v partial reduce.
// C[m,n] = dot(enc[m,:], attn_W[n, H:2H])   (m = b*S+s, n = h)
// part[m, blockIdx.y] = sum over this block's 64 n of v[n]*tanh(q[b,n]+C)
// M=16384, N=1024, K=1024. 64x64 tile, BK=16, 256 thr, 4x4 per thread.
// ---------------------------------------------------------------------------
__global__ __launch_bounds__(256) void k_energy(const float* __restrict__ enc,
                                                const float* __restrict__ attn_W,
                                                const float* __restrict__ q,
                                                const float* __restrict__ v,
                                                float* __restrict__ part) {
    __shared__ __align__(16) float As[16][68];
    __shared__ __align__(16) float Bs[16][68];
    __shared__ float red[64][17];

    const int m0 = blockIdx.x * 64;   // 256 tiles
    const int n0 = blockIdx.y * 64;   // 16 tiles
    const int tid = threadIdx.x;
    const int ty = tid >> 4, tx = tid & 15;
    const int lr = tid >> 2;          // 0..63 (tile row for loads)
    const int lk = (tid & 3) * 4;     // k quad

    float C[4][4] = {};

    for (int k0 = 0; k0 < H; k0 += 16) {
        float4 a4 = *(const float4*)(enc + (size_t)(m0 + lr) * H + k0 + lk);
        float4 b4 = *(const float4*)(attn_W + (size_t)(n0 + lr) * H2 + H + k0 + lk);
        __syncthreads();
        As[lk + 0][lr] = a4.x; As[lk + 1][lr] = a4.y;
        As[lk + 2][lr] = a4.z; As[lk + 3][lr] = a4.w;
        Bs[lk + 0][lr] = b4.x; Bs[lk + 1][lr] = b4.y;
        Bs[lk + 2][lr] = b4.z; Bs[lk + 3][lr] = b4.w;
        __syncthreads();
#pragma unroll
        for (int k = 0; k < 16; k++) {
            float4 av = *(const float4*)&As[k][ty * 4];
            float4 bv = *(const float4*)&Bs[k][tx * 4];
            float a[4] = {av.x, av.y, av.z, av.w};
            float bb[4] = {bv.x, bv.y, bv.z, bv.w};
#pragma unroll
            for (int i = 0; i < 4; i++)
#pragma unroll
                for (int j = 0; j < 4; j++) C[i][j] += a[i] * bb[j];
        }
    }

    // epilogue: v[n]*tanh(q[b,n]+C), partial row-sum over this block's 64 cols
    const float* qrow = q + (size_t)(m0 >> 7) * H;  // b is constant per block
#pragma unroll
    for (int i = 0; i < 4; i++) {
        float rs = 0.f;
#pragma unroll
        for (int j = 0; j < 4; j++) {
            int n = n0 + tx * 4 + j;
            rs += v[n] * tanhf(qrow[n] + C[i][j]);
        }
        red[ty * 4 + i][tx] = rs;
    }
    __syncthreads();
    if (tid < 64) {
        float s = 0.f;
#pragma unroll
        for (int t = 0; t < 16; t++) s += red[tid][t];
        part[(size_t)(m0 + tid) * 16 + blockIdx.y] = s;
    }
}

// ---------------------------------------------------------------------------
// Kernel 3: per-b softmax over S + context = sum_s w[s]*enc[b,s,:]
// One block per b (128 blocks, 256 threads). Also writes attn_weights output.
// ---------------------------------------------------------------------------
__global__ __launch_bounds__(256) void k_softmax_ctx(const float* __restrict__ part,
                                                     const float* __restrict__ enc,
                                                     float* __restrict__ attn_out,
                                                     float* __restrict__ ctxout) {
    const int b = blockIdx.x;
    const int tid = threadIdx.x;
    __shared__ float w[S];
    __shared__ float sred[2];

    if (tid < S) {
        const float* p = part + (size_t)(b * S + tid) * 16;
        float s = 0.f;
#pragma unroll
        for (int t = 0; t < 16; t++) s += p[t];
        w[tid] = s;
    }
    __syncthreads();
    if (tid == 0) {
        float m = w[0];
        for (int i = 1; i < S; i++) m = fmaxf(m, w[i]);
        sred[0] = m;
    }
    __syncthreads();
    if (tid < S) w[tid] = expf(w[tid] - sred[0]);
    __syncthreads();
    if (tid == 0) {
        float s = 0.f;
        for (int i = 0; i < S; i++) s += w[i];
        sred[1] = s;
    }
    __syncthreads();
    if (tid < S) {
        w[tid] /= sred[1];
        attn_out[b * S + tid] = w[tid];
    }
    __syncthreads();

    // context: threads cover h contiguously (coalesced), loop over s
    for (int hb = 0; hb < H / 256; hb++) {
        int h = hb * 256 + tid;
        const float* e = enc + (size_t)b * S * H + h;
        float acc = 0.f;
#pragma unroll 4
        for (int s = 0; s < S; s++) acc += w[s] * e[(size_t)s * H];
        ctxout[(size_t)b * H + h] = acc;
    }
}

// ---------------------------------------------------------------------------
// Kernel 4: gates GEMM. gates[b,j] = xin[b,:]@W_ih[j,:] + h[b,:]@W_hh[j,:] + biases
// Virtual A: [emb(x[b]) | context | h_last], K = 2560. M=128, N=4096.
// 32x64 tile, BK=16, 256 thr, 2x4 per thread -> grid (4,64)=256 blocks.
// ---------------------------------------------------------------------------
__global__ __launch_bounds__(256) void k_gates(const int* __restrict__ x,
                                               const float* __restrict__ emb,
                                               const float* __restrict__ ctx,
                                               const float* __restrict__ hlast,
                                               const float* __restrict__ W_ih,
                                               const float* __restrict__ W_hh,
                                               const float* __restrict__ b_ih,
                                               const float* __restrict__ b_hh,
                                               float* __restrict__ gates) {
    __shared__ __align__(16) float As[16][36];
    __shared__ __align__(16) float Bs[16][68];
    const int m0 = blockIdx.x * 32;
    const int n0 = blockIdx.y * 64;
    const int tid = threadIdx.x;
    const int ty = tid >> 4, tx = tid & 15;
    const int lr = tid >> 2;
    const int lk = (tid & 3) * 4;

    float C[2][4] = {};

    for (int k0 = 0; k0 < KG; k0 += 16) {
        float4 a4 = {0, 0, 0, 0}, b4;
        if (tid < 128) {  // A tile: 32 rows x 16 k = 128 float4
            int r = m0 + lr;
            int kk = k0 + lk;
            const float* src;
            if (kk < E)        src = emb + (size_t)x[r] * E + kk;
            else if (kk < KX)  src = ctx + (size_t)r * H + (kk - E);
            else               src = hlast + (size_t)r * H + (kk - KX);
            a4 = *(const float4*)src;
        }
        {   // B tile: 64 rows x 16 k = 256 float4
            int n = n0 + lr;
            int kk = k0 + lk;
            const float* src = (kk < KX) ? (W_ih + (size_t)n * KX + kk)
                                         : (W_hh + (size_t)n * H + (kk - KX));
            b4 = *(const float4*)src;
        }
        __syncthreads();
        if (tid < 128) {
            As[lk + 0][lr] = a4.x; As[lk + 1][lr] = a4.y;
            As[lk + 2][lr] = a4.z; As[lk + 3][lr] = a4.w;
        }
        Bs[lk + 0][lr] = b4.x; Bs[lk + 1][lr] = b4.y;
        Bs[lk + 2][lr] = b4.z; Bs[lk + 3][lr] = b4.w;
        __syncthreads();
#pragma unroll
        for (int k = 0; k < 16; k++) {
            float a0 = As[k][ty * 2], a1 = As[k][ty * 2 + 1];
            float4 bv = *(const float4*)&Bs[k][tx * 4];
            C[0][0] += a0 * bv.x; C[0][1] += a0 * bv.y;
            C[0][2] += a0 * bv.z; C[0][3] += a0 * bv.w;
            C[1][0] += a1 * bv.x; C[1][1] += a1 * bv.y;
            C[1][2] += a1 * bv.z; C[1][3] += a1 * bv.w;
        }
    }
#pragma unroll
    for (int i = 0; i < 2; i++)
#pragma unroll
        for (int j = 0; j < 4; j++) {
            int r = m0 + ty * 2 + i;
            int n = n0 + tx * 4 + j;
            gates[(size_t)r * G4 + n] = C[i][j] + b_ih[n] + b_hh[n];
        }
}

// ---------------------------------------------------------------------------
// Kernel 5: LSTM pointwise + build xout = [h_new | context]
// ---------------------------------------------------------------------------
__global__ __launch_bounds__(256) void k_lstm(const float* __restrict__ gates,
                                              const float* __restrict__ cell,
                                              const float* __restrict__ ctx,
                                              float* __restrict__ out_h,
                                              float* __restrict__ out_c,
                                              float* __restrict__ xout) {
    int idx = blockIdx.x * 256 + threadIdx.x;  // 512 blocks = B*H
    int b = idx >> 10;
    int h = idx & (H - 1);
    const float* g = gates + (size_t)b * G4;
    float ig = g[h], fg = g[H + h], gg = g[2 * H + h], og = g[3 * H + h];
    float si = 1.f / (1.f + expf(-ig));
    float sf = 1.f / (1.f + expf(-fg));
    float so = 1.f / (1.f + expf(-og));
    float c = sf * cell[idx] + si * tanhf(gg);
    float hn = so * tanhf(c);
    out_h[idx] = hn;
    out_c[idx] = c;
    xout[(size_t)b * H2 + h] = hn;
    xout[(size_t)b * H2 + H + h] = ctx[idx];
}

// ---------------------------------------------------------------------------
// Kernel 6: fc GEMM. logits[b,n] = xout[b,:]@fc_W[n,:] + fc_b[n]
// M=128, N=32000, K=2048. 64x64 tile, BK=16, 4x4/thread -> grid (2,500).
// ---------------------------------------------------------------------------
__global__ __launch_bounds__(256) void k_fc(const float* __restrict__ xo,
                                            const float* __restrict__ fcW,
                                            const float* __restrict__ fcb,
                                            float* __restrict__ logits) {
    __shared__ __align__(16) float As[16][68];
    __shared__ __align__(16) float Bs[16][68];
    const int m0 = blockIdx.x * 64;
    const int n0 = blockIdx.y * 64;
    const int tid = threadIdx.x;
    const int ty = tid >> 4, tx = tid & 15;
    const int lr = tid >> 2;
    const int lk = (tid & 3) * 4;

    float C[4][4] = {};

    for (int k0 = 0; k0 < H2; k0 += 16) {
        float4 a4 = *(const float4*)(xo + (size_t)(m0 + lr) * H2 + k0 + lk);
        float4 b4 = *(const float4*)(fcW + (size_t)(n0 + lr) * H2 + k0 + lk);
        __syncthreads();
        As[lk + 0][lr] = a4.x; As[lk + 1][lr] = a4.y;
        As[lk + 2][lr] = a4.z; As[lk + 3][lr] = a4.w;
        Bs[lk + 0][lr] = b4.x; Bs[lk + 1][lr] = b4.y;
        Bs[lk + 2][lr] = b4.z; Bs[lk + 3][lr] = b4.w;
        __syncthreads();
#pragma unroll
        for (int k = 0; k < 16; k++) {
            float4 av = *(const float4*)&As[k][ty * 4];
            float4 bv = *(const float4*)&Bs[k][tx * 4];
            float a[4] = {av.x, av.y, av.z, av.w};
            float bb[4] = {bv.x, bv.y, bv.z, bv.w};
#pragma unroll
            for (int i = 0; i < 4; i++)
#pragma unroll
                for (int j = 0; j < 4; j++) C[i][j] += a[i] * bb[j];
        }
    }
#pragma unroll
    for (int i = 0; i < 4; i++)
#pragma unroll
        for (int j = 0; j < 4; j++) {
            int r = m0 + ty * 4 + i;
            int n = n0 + tx * 4 + j;
            logits[(size_t)r * V + n] = C[i][j] + fcb[n];
        }
}

// ---------------------------------------------------------------------------
extern "C" void kernel_launch(void* const* d_in, const int* in_sizes, int n_in,
                              void* d_out, int out_size, void* d_ws, size_t ws_size,
                              hipStream_t stream) {
    const int*   x      = (const int*)d_in[0];
    const float* hidden = (const float*)d_in[1];   // [1,B,H] -> h_last
    const float* cell   = (const float*)d_in[2];   // [1,B,H] -> c_last
    const float* enc    = (const float*)d_in[3];   // [B,S,H]
    const float* emb    = (const float*)d_in[4];   // [V,E]
    const float* attn_W = (const float*)d_in[5];   // [H,2H]
    const float* attn_b = (const float*)d_in[6];   // [H]
    const float* v      = (const float*)d_in[7];   // [H]
    const float* W_ih   = (const float*)d_in[8];   // [4H, E+H]
    const float* W_hh   = (const float*)d_in[9];   // [4H, H]
    const float* b_ih   = (const float*)d_in[10];  // [4H]
    const float* b_hh   = (const float*)d_in[11];  // [4H]
    const float* fc_W   = (const float*)d_in[12];  // [V, 2H]
    const float* fc_b   = (const float*)d_in[13];  // [V]

    float* out = (float*)d_out;
    float* logits   = out;                                   // [B,V]
    float* out_h    = out + (size_t)B * V;                   // [1,B,H]
    float* out_c    = out_h + (size_t)B * H;                 // [1,B,H]
    float* out_attn = out_c + (size_t)B * H;                 // [B,S]

    float* ws    = (float*)d_ws;
    float* q     = ws;                       // B*H      = 131072
    float* part  = q + (size_t)B * H;        // BS*16    = 262144
    float* ctx   = part + (size_t)BS * 16;   // B*H      = 131072
    float* gates = ctx + (size_t)B * H;      // B*4H     = 524288
    float* xout  = gates + (size_t)B * G4;   // B*2H     = 262144
    // total ws: ~5.3 MB of floats

    k_q<<<dim3(B * H / 256), dim3(256), 0, stream>>>(hidden, attn_W, attn_b, q);
    k_energy<<<dim3(BS / 64, H / 64), dim3(256), 0, stream>>>(enc, attn_W, q, v, part);
    k_softmax_ctx<<<dim3(B), dim3(256), 0, stream>>>(part, enc, out_attn, ctx);
    k_gates<<<dim3(B / 32, G4 / 64), dim3(256), 0, stream>>>(
        x, emb, ctx, hidden, W_ih, W_hh, b_ih, b_hh, gates);
    k_lstm<<<dim3(B * H / 256), dim3(256), 0, stream>>>(gates, cell, ctx, out_h, out_c, xout);
    k_fc<<<dim3(B / 64, V / 64), dim3(256), 0, stream>>>(xout, fc_W, fc_b, logits);
}

// Round 2
// 806.356 us; speedup vs baseline: 1.6585x; 1.6585x over previous
//
#include <hip/hip_runtime.h>
#include <hip/hip_bf16.h>
#include <math.h>

// Problem constants
constexpr int B  = 128;
constexpr int S  = 128;
constexpr int H  = 1024;
constexpr int E  = 512;
constexpr int V  = 32000;
constexpr int H2 = 2 * H;     // 2048
constexpr int G4 = 4 * H;     // 4096
constexpr int KX = E + H;     // 1536
constexpr int KG = KX + H;    // 2560
constexpr int BS = B * S;     // 16384

typedef float  f32x4  __attribute__((ext_vector_type(4)));
typedef short  short8 __attribute__((ext_vector_type(8)));

// fp32 -> bf16 with round-to-nearest-even
__device__ __forceinline__ short f2bf(float f) {
    union { float f; unsigned u; } x; x.f = f;
    unsigned r = (x.u + 0x7FFFu + ((x.u >> 16) & 1u)) >> 16;
    return (short)r;
}
__device__ __forceinline__ float bf2f(unsigned short u) {
    union { unsigned u; float f; } x; x.u = ((unsigned)u) << 16;
    return x.f;
}
__device__ __forceinline__ float fast_tanh(float x) {
    float z = fminf(fmaxf(x, -15.f), 15.f);
    float e = __expf(2.f * z);
    return 1.f - __fdividef(2.f, e + 1.f);
}
// async global->LDS, 16 bytes per lane; lds dest = uniform base + lane*16
__device__ __forceinline__ void glds16(const void* g, void* l) {
    __builtin_amdgcn_global_load_lds(
        (const __attribute__((address_space(1))) unsigned int*)g,
        (__attribute__((address_space(3))) unsigned int*)l,
        16, 0, 0);
}

// ---------------------------------------------------------------------------
// Convert enc (B*S*H fp32) -> bf16
// ---------------------------------------------------------------------------
__global__ __launch_bounds__(256) void k_cvt_enc(const float* __restrict__ src,
                                                 short* __restrict__ dst) {
    int p = blockIdx.x * 256 + threadIdx.x;           // float4 index
    float4 a = *(const float4*)(src + (size_t)p * 4);
    short4 o = { f2bf(a.x), f2bf(a.y), f2bf(a.z), f2bf(a.w) };
    *(short4*)(dst + (size_t)p * 4) = o;
}

// Convert attn_W[:, H:2H] -> w2b[1024][1024] bf16
__global__ __launch_bounds__(256) void k_cvt_w2(const float* __restrict__ attn_W,
                                                short* __restrict__ w2b) {
    int p = blockIdx.x * 256 + threadIdx.x;           // 262144 float4 units
    int row = p >> 8;                                 // 256 f4 per row
    int c = (p & 255) * 4;
    float4 a = *(const float4*)(attn_W + (size_t)row * H2 + H + c);
    short4 o = { f2bf(a.x), f2bf(a.y), f2bf(a.z), f2bf(a.w) };
    *(short4*)(w2b + (size_t)row * H + c) = o;
}

// ---------------------------------------------------------------------------
// q[b,h] = attn_b[h] + dot(h_last[b,:], attn_W[h, 0:H])   (fp32, L2-resident)
// ---------------------------------------------------------------------------
__global__ __launch_bounds__(256) void k_q(const float* __restrict__ hlast,
                                           const float* __restrict__ attn_W,
                                           const float* __restrict__ attn_b,
                                           float* __restrict__ q) {
    int idx = blockIdx.x * 256 + threadIdx.x;
    int b = idx >> 10;
    int h = idx & (H - 1);
    const float* arow = attn_W + (size_t)h * H2;
    const float* hrow = hlast + (size_t)b * H;
    float acc = 0.f;
    for (int k = 0; k < H; k += 4) {
        float4 a = *(const float4*)(arow + k);
        float4 x = *(const float4*)(hrow + k);
        acc += a.x * x.x + a.y * x.y + a.z * x.z + a.w * x.w;
    }
    q[idx] = acc + attn_b[h];
}

// ---------------------------------------------------------------------------
// Energy MFMA GEMM + fused tanh/v/row-reduce.
// C[m,n] = dot(encb[m,:], w2b[n,:]); part[m][blockIdx.y] = sum_n v*tanh(q+C)
// M=16384 N=1024 K=1024. BM=BN=128, BK=32, 256 thr (4 waves), 16x16x32 bf16.
// blockIdx.x == b (since BM == S).
// ---------------------------------------------------------------------------
__global__ __launch_bounds__(256) void k_energy_mfma(const short* __restrict__ encb,
                                                     const short* __restrict__ w2b,
                                                     const float* __restrict__ q,
                                                     const float* __restrict__ v,
                                                     float* __restrict__ part) {
    __shared__ __align__(16) short A_s[128 * 32];
    __shared__ __align__(16) short B_s[128 * 32];
    __shared__ float red[128][33];

    const int tid  = threadIdx.x;
    const int wave = tid >> 6, lane = tid & 63;
    const int wr = wave >> 1, wc = wave & 1;
    const int c16 = lane & 15, q4 = lane >> 4;
    const int m0 = blockIdx.x * 128;
    const int n0 = blockIdx.y * 128;

    f32x4 acc[4][4] = {};

    // staging units: 16B each; wave handles units [wave*128, wave*128+128)
    const int u0 = wave * 128 + lane;
    const int rowA0 = u0 >> 2,        rowA1 = (u0 + 64) >> 2;
    const int ofsA0 = (u0 & 3) * 8,   ofsA1 = ((u0 + 64) & 3) * 8;
    short* ldsA0 = A_s + wave * 1024;
    short* ldsA1 = A_s + wave * 1024 + 512;
    short* ldsB0 = B_s + wave * 1024;
    short* ldsB1 = B_s + wave * 1024 + 512;
    const short* gA = encb + (size_t)m0 * H;
    const short* gB = w2b + (size_t)n0 * H;

    for (int k0 = 0; k0 < H; k0 += 32) {
        __syncthreads();
        glds16(gA + (size_t)rowA0 * H + k0 + ofsA0, ldsA0);
        glds16(gA + (size_t)rowA1 * H + k0 + ofsA1, ldsA1);
        glds16(gB + (size_t)rowA0 * H + k0 + ofsA0, ldsB0);
        glds16(gB + (size_t)rowA1 * H + k0 + ofsA1, ldsB1);
        __syncthreads();

        short8 a[4], b[4];
#pragma unroll
        for (int i = 0; i < 4; i++)
            a[i] = *(const short8*)(A_s + (wr * 64 + i * 16 + c16) * 32 + q4 * 8);
#pragma unroll
        for (int j = 0; j < 4; j++)
            b[j] = *(const short8*)(B_s + (wc * 64 + j * 16 + c16) * 32 + q4 * 8);
#pragma unroll
        for (int i = 0; i < 4; i++)
#pragma unroll
            for (int j = 0; j < 4; j++)
                acc[i][j] = __builtin_amdgcn_mfma_f32_16x16x32_bf16(a[i], b[j], acc[i][j], 0, 0, 0);
    }

    // epilogue: e = v[n]*tanh(q[b,n]+C); partial row-sums into red
    const float* qb = q + (size_t)blockIdx.x * H;   // b == blockIdx.x
#pragma unroll
    for (int i = 0; i < 4; i++) {
#pragma unroll
        for (int r = 0; r < 4; r++) {
            float s = 0.f;
#pragma unroll
            for (int j = 0; j < 4; j++) {
                int n = n0 + wc * 64 + j * 16 + c16;
                s += v[n] * fast_tanh(qb[n] + acc[i][j][r]);
            }
            red[wr * 64 + i * 16 + q4 * 4 + r][wc * 16 + c16] = s;
        }
    }
    __syncthreads();
    if (tid < 128) {
        float s = 0.f;
#pragma unroll
        for (int c = 0; c < 32; c++) s += red[tid][c];
        part[(size_t)(m0 + tid) * 8 + blockIdx.y] = s;
    }
}

// ---------------------------------------------------------------------------
// per-b softmax over S + context = sum_s w[s]*enc_bf16[b,s,:]
// ---------------------------------------------------------------------------
__global__ __launch_bounds__(256) void k_softmax_ctx(const float* __restrict__ part,
                                                     const short* __restrict__ encb,
                                                     float* __restrict__ attn_out,
                                                     float* __restrict__ ctxout) {
    const int b = blockIdx.x;
    const int tid = threadIdx.x;
    __shared__ float w[S];
    __shared__ float sred[2];

    if (tid < S) {
        const float* p = part + (size_t)(b * S + tid) * 8;
        float s = 0.f;
#pragma unroll
        for (int t = 0; t < 8; t++) s += p[t];
        w[tid] = s;
    }
    __syncthreads();
    if (tid == 0) {
        float m = w[0];
        for (int i = 1; i < S; i++) m = fmaxf(m, w[i]);
        sred[0] = m;
    }
    __syncthreads();
    if (tid < S) w[tid] = expf(w[tid] - sred[0]);
    __syncthreads();
    if (tid == 0) {
        float s = 0.f;
        for (int i = 0; i < S; i++) s += w[i];
        sred[1] = s;
    }
    __syncthreads();
    if (tid < S) {
        w[tid] /= sred[1];
        attn_out[b * S + tid] = w[tid];
    }
    __syncthreads();

    for (int hb = 0; hb < H / 256; hb++) {
        int h = hb * 256 + tid;
        const unsigned short* e = (const unsigned short*)encb + (size_t)b * S * H + h;
        float acc = 0.f;
#pragma unroll 4
        for (int s = 0; s < S; s++) acc += w[s] * bf2f(e[(size_t)s * H]);
        ctxout[(size_t)b * H + h] = acc;
    }
}

// ---------------------------------------------------------------------------
// gates GEMM (fp32, accuracy buffer). M=128, N=4096, K=2560 virtual concat.
// ---------------------------------------------------------------------------
__global__ __launch_bounds__(256) void k_gates(const int* __restrict__ x,
                                               const float* __restrict__ emb,
                                               const float* __restrict__ ctx,
                                               const float* __restrict__ hlast,
                                               const float* __restrict__ W_ih,
                                               const float* __restrict__ W_hh,
                                               const float* __restrict__ b_ih,
                                               const float* __restrict__ b_hh,
                                               float* __restrict__ gates) {
    __shared__ __align__(16) float As[16][36];
    __shared__ __align__(16) float Bs[16][68];
    const int m0 = blockIdx.x * 32;
    const int n0 = blockIdx.y * 64;
    const int tid = threadIdx.x;
    const int ty = tid >> 4, tx = tid & 15;
    const int lr = tid >> 2;
    const int lk = (tid & 3) * 4;

    float C[2][4] = {};

    for (int k0 = 0; k0 < KG; k0 += 16) {
        float4 a4 = {0, 0, 0, 0}, b4;
        if (tid < 128) {
            int r = m0 + lr;
            int kk = k0 + lk;
            const float* src;
            if (kk < E)        src = emb + (size_t)x[r] * E + kk;
            else if (kk < KX)  src = ctx + (size_t)r * H + (kk - E);
            else               src = hlast + (size_t)r * H + (kk - KX);
            a4 = *(const float4*)src;
        }
        {
            int n = n0 + lr;
            int kk = k0 + lk;
            const float* src = (kk < KX) ? (W_ih + (size_t)n * KX + kk)
                                         : (W_hh + (size_t)n * H + (kk - KX));
            b4 = *(const float4*)src;
        }
        __syncthreads();
        if (tid < 128) {
            As[lk + 0][lr] = a4.x; As[lk + 1][lr] = a4.y;
            As[lk + 2][lr] = a4.z; As[lk + 3][lr] = a4.w;
        }
        Bs[lk + 0][lr] = b4.x; Bs[lk + 1][lr] = b4.y;
        Bs[lk + 2][lr] = b4.z; Bs[lk + 3][lr] = b4.w;
        __syncthreads();
#pragma unroll
        for (int k = 0; k < 16; k++) {
            float a0 = As[k][ty * 2], a1 = As[k][ty * 2 + 1];
            float4 bv = *(const float4*)&Bs[k][tx * 4];
            C[0][0] += a0 * bv.x; C[0][1] += a0 * bv.y;
            C[0][2] += a0 * bv.z; C[0][3] += a0 * bv.w;
            C[1][0] += a1 * bv.x; C[1][1] += a1 * bv.y;
            C[1][2] += a1 * bv.z; C[1][3] += a1 * bv.w;
        }
    }
#pragma unroll
    for (int i = 0; i < 2; i++)
#pragma unroll
        for (int j = 0; j < 4; j++) {
            int r = m0 + ty * 2 + i;
            int n = n0 + tx * 4 + j;
            gates[(size_t)r * G4 + n] = C[i][j] + b_ih[n] + b_hh[n];
        }
}

// ---------------------------------------------------------------------------
// LSTM pointwise; also emits xout = [h_new | context] as bf16 for fc.
// ---------------------------------------------------------------------------
__global__ __launch_bounds__(256) void k_lstm(const float* __restrict__ gates,
                                              const float* __restrict__ cell,
                                              const float* __restrict__ ctx,
                                              float* __restrict__ out_h,
                                              float* __restrict__ out_c,
                                              short* __restrict__ xoutb) {
    int idx = blockIdx.x * 256 + threadIdx.x;
    int b = idx >> 10;
    int h = idx & (H - 1);
    const float* g = gates + (size_t)b * G4;
    float ig = g[h], fg = g[H + h], gg = g[2 * H + h], og = g[3 * H + h];
    float si = 1.f / (1.f + expf(-ig));
    float sf = 1.f / (1.f + expf(-fg));
    float so = 1.f / (1.f + expf(-og));
    float c = sf * cell[idx] + si * tanhf(gg);
    float hn = so * tanhf(c);
    out_h[idx] = hn;
    out_c[idx] = c;
    xoutb[(size_t)b * H2 + h] = f2bf(hn);
    xoutb[(size_t)b * H2 + H + h] = f2bf(ctx[idx]);
}

// ---------------------------------------------------------------------------
// fc MFMA GEMM: logits[m,n] = xoutb[m,:]@fc_W[n,:] + fc_b[n]
// M=128 N=32000 K=2048. BM=128, BN=64, BK=32. fc_W converted inline fp32->bf16
// with a register-prefetch pipeline (the 262 MB stream is the bottleneck).
// ---------------------------------------------------------------------------
__global__ __launch_bounds__(256) void k_fc_mfma(const short* __restrict__ xoutb,
                                                 const float* __restrict__ fcW,
                                                 const float* __restrict__ fcb,
                                                 float* __restrict__ logits) {
    __shared__ __align__(16) short A_s[128 * 32];
    __shared__ __align__(16) short B_s[64 * 32];

    const int tid  = threadIdx.x;
    const int wave = tid >> 6, lane = tid & 63;
    const int wr = wave >> 1, wc = wave & 1;
    const int c16 = lane & 15, q4 = lane >> 4;
    const int n0 = blockIdx.x * 64;

    f32x4 acc[4][2] = {};

    // A staging via global_load_lds: 512 units of 16B
    const int u0 = wave * 128 + lane;
    const int rowA0 = u0 >> 2,        rowA1 = (u0 + 64) >> 2;
    const int ofsA0 = (u0 & 3) * 8,   ofsA1 = ((u0 + 64) & 3) * 8;
    short* ldsA0 = A_s + wave * 1024;
    short* ldsA1 = A_s + wave * 1024 + 512;

    // B: 64x32 fp32 = 512 float4 units; thread handles p0 = tid, p1 = tid+256
    const int rB0 = tid >> 3,           rB1 = (tid + 256) >> 3;
    const int cB0 = (tid & 7) * 4,      cB1 = cB0;     // (p&7) same for p,p+256
    const float* gB0 = fcW + (size_t)(n0 + rB0) * H2 + cB0;
    const float* gB1 = fcW + (size_t)(n0 + rB1) * H2 + cB1;

    float4 pb0 = *(const float4*)(gB0);
    float4 pb1 = *(const float4*)(gB1);

    for (int kk = 0; kk < H2 / 32; kk++) {
        const int k0 = kk * 32;
        __syncthreads();
        // write prefetched B (converted) to LDS
        short4 w0 = { f2bf(pb0.x), f2bf(pb0.y), f2bf(pb0.z), f2bf(pb0.w) };
        short4 w1 = { f2bf(pb1.x), f2bf(pb1.y), f2bf(pb1.z), f2bf(pb1.w) };
        *(short4*)(B_s + rB0 * 32 + cB0) = w0;
        *(short4*)(B_s + rB1 * 32 + cB1) = w1;
        // stage A for this k-block
        glds16(xoutb + (size_t)rowA0 * H2 + k0 + ofsA0, ldsA0);
        glds16(xoutb + (size_t)rowA1 * H2 + k0 + ofsA1, ldsA1);
        __syncthreads();
        // prefetch next B (stays in flight across compute)
        if (kk < H2 / 32 - 1) {
            pb0 = *(const float4*)(gB0 + k0 + 32);
            pb1 = *(const float4*)(gB1 + k0 + 32);
        }

        short8 a[4], b[2];
#pragma unroll
        for (int i = 0; i < 4; i++)
            a[i] = *(const short8*)(A_s + (wr * 64 + i * 16 + c16) * 32 + q4 * 8);
#pragma unroll
        for (int j = 0; j < 2; j++)
            b[j] = *(const short8*)(B_s + (wc * 32 + j * 16 + c16) * 32 + q4 * 8);
#pragma unroll
        for (int i = 0; i < 4; i++)
#pragma unroll
            for (int j = 0; j < 2; j++)
                acc[i][j] = __builtin_amdgcn_mfma_f32_16x16x32_bf16(a[i], b[j], acc[i][j], 0, 0, 0);
    }

#pragma unroll
    for (int i = 0; i < 4; i++)
#pragma unroll
        for (int j = 0; j < 2; j++)
#pragma unroll
            for (int r = 0; r < 4; r++) {
                int R = wr * 64 + i * 16 + q4 * 4 + r;
                int n = n0 + wc * 32 + j * 16 + c16;
                logits[(size_t)R * V + n] = acc[i][j][r] + fcb[n];
            }
}

// ---------------------------------------------------------------------------
extern "C" void kernel_launch(void* const* d_in, const int* in_sizes, int n_in,
                              void* d_out, int out_size, void* d_ws, size_t ws_size,
                              hipStream_t stream) {
    const int*   x      = (const int*)d_in[0];
    const float* hidden = (const float*)d_in[1];
    const float* cell   = (const float*)d_in[2];
    const float* enc    = (const float*)d_in[3];
    const float* emb    = (const float*)d_in[4];
    const float* attn_W = (const float*)d_in[5];
    const float* attn_b = (const float*)d_in[6];
    const float* v      = (const float*)d_in[7];
    const float* W_ih   = (const float*)d_in[8];
    const float* W_hh   = (const float*)d_in[9];
    const float* b_ih   = (const float*)d_in[10];
    const float* b_hh   = (const float*)d_in[11];
    const float* fc_W   = (const float*)d_in[12];
    const float* fc_b   = (const float*)d_in[13];

    float* out = (float*)d_out;
    float* logits   = out;                                   // [B,V]
    float* out_h    = out + (size_t)B * V;                   // [1,B,H]
    float* out_c    = out_h + (size_t)B * H;                 // [1,B,H]
    float* out_attn = out_c + (size_t)B * H;                 // [B,S]

    // workspace layout (all 16B-aligned); total ~39.9 MB
    char* ws = (char*)d_ws;
    short* encb  = (short*)ws;                        ws += (size_t)BS * H * 2;   // 33.5 MB
    short* w2b   = (short*)ws;                        ws += (size_t)H * H * 2;    // 2 MB
    short* xoutb = (short*)ws;                        ws += (size_t)B * H2 * 2;   // 0.5 MB
    float* q     = (float*)ws;                        ws += (size_t)B * H * 4;
    float* part  = (float*)ws;                        ws += (size_t)BS * 8 * 4;
    float* ctx   = (float*)ws;                        ws += (size_t)B * H * 4;
    float* gates = (float*)ws;                        ws += (size_t)B * G4 * 4;

    k_cvt_enc<<<dim3(BS * H / 1024), dim3(256), 0, stream>>>(enc, encb);
    k_cvt_w2<<<dim3(H * H / 1024), dim3(256), 0, stream>>>(attn_W, w2b);
    k_q<<<dim3(B * H / 256), dim3(256), 0, stream>>>(hidden, attn_W, attn_b, q);
    k_energy_mfma<<<dim3(BS / 128, H / 128), dim3(256), 0, stream>>>(encb, w2b, q, v, part);
    k_softmax_ctx<<<dim3(B), dim3(256), 0, stream>>>(part, encb, out_attn, ctx);
    k_gates<<<dim3(B / 32, G4 / 64), dim3(256), 0, stream>>>(
        x, emb, ctx, hidden, W_ih, W_hh, b_ih, b_hh, gates);
    k_lstm<<<dim3(B * H / 256), dim3(256), 0, stream>>>(gates, cell, ctx, out_h, out_c, xoutb);
    k_fc_mfma<<<dim3(V / 64), dim3(256), 0, stream>>>(xoutb, fc_W, fc_b, logits);
}

// Round 3
// 705.721 us; speedup vs baseline: 1.8951x; 1.1426x over previous
//
#include <hip/hip_runtime.h>
#include <hip/hip_bf16.h>
#include <math.h>

// Problem constants
constexpr int B  = 128;
constexpr int S  = 128;
constexpr int H  = 1024;
constexpr int E  = 512;
constexpr int V  = 32000;
constexpr int H2 = 2 * H;     // 2048
constexpr int G4 = 4 * H;     // 4096
constexpr int KX = E + H;     // 1536
constexpr int KG = KX + H;    // 2560
constexpr int BS = B * S;     // 16384

typedef float  f32x4  __attribute__((ext_vector_type(4)));
typedef short  short8 __attribute__((ext_vector_type(8)));

// fp32 -> bf16 round-to-nearest-even
__device__ __forceinline__ short f2bf(float f) {
    union { float f; unsigned u; } x; x.f = f;
    unsigned r = (x.u + 0x7FFFu + ((x.u >> 16) & 1u)) >> 16;
    return (short)r;
}
__device__ __forceinline__ float bf2f(unsigned short u) {
    union { unsigned u; float f; } x; x.u = ((unsigned)u) << 16;
    return x.f;
}
__device__ __forceinline__ float fast_tanh(float x) {
    float z = fminf(fmaxf(x, -15.f), 15.f);
    float e = __expf(2.f * z);
    return 1.f - __fdividef(2.f, e + 1.f);
}
// async global->LDS, 16B/lane; LDS dest = wave-uniform base + lane*16
__device__ __forceinline__ void glds16(const void* g, void* l) {
    __builtin_amdgcn_global_load_lds(
        (const __attribute__((address_space(1))) unsigned int*)g,
        (__attribute__((address_space(3))) unsigned int*)l,
        16, 0, 0);
}

// ---------------------------------------------------------------------------
// Merged convert: enc (B*S*H) -> bf16, and attn_W[:, H:2H] -> w2b bf16.
// Blocks [0, 16384): enc. Blocks [16384, 17408): w2.
// ---------------------------------------------------------------------------
__global__ __launch_bounds__(256) void k_cvt(const float* __restrict__ enc,
                                             short* __restrict__ encb,
                                             const float* __restrict__ attn_W,
                                             short* __restrict__ w2b) {
    int bid = blockIdx.x;
    if (bid < 16384) {
        size_t p = (size_t)bid * 256 + threadIdx.x;     // float4 index
        float4 a = *(const float4*)(enc + p * 4);
        short4 o = { f2bf(a.x), f2bf(a.y), f2bf(a.z), f2bf(a.w) };
        *(short4*)(encb + p * 4) = o;
    } else {
        int p = (bid - 16384) * 256 + threadIdx.x;      // 262144 float4 units
        int row = p >> 8;
        int c = (p & 255) * 4;
        float4 a = *(const float4*)(attn_W + (size_t)row * H2 + H + c);
        short4 o = { f2bf(a.x), f2bf(a.y), f2bf(a.z), f2bf(a.w) };
        *(short4*)(w2b + (size_t)row * H + c) = o;
    }
}

// ---------------------------------------------------------------------------
// q[b,h] = attn_b[h] + dot(h_last[b,:], attn_W[h, 0:H])   (fp32, L2-resident)
// ---------------------------------------------------------------------------
__global__ __launch_bounds__(256) void k_q(const float* __restrict__ hlast,
                                           const float* __restrict__ attn_W,
                                           const float* __restrict__ attn_b,
                                           float* __restrict__ q) {
    int idx = blockIdx.x * 256 + threadIdx.x;
    int b = idx >> 10;
    int h = idx & (H - 1);
    const float* arow = attn_W + (size_t)h * H2;
    const float* hrow = hlast + (size_t)b * H;
    float acc = 0.f;
    for (int k = 0; k < H; k += 4) {
        float4 a = *(const float4*)(arow + k);
        float4 x = *(const float4*)(hrow + k);
        acc += a.x * x.x + a.y * x.y + a.z * x.z + a.w * x.w;
    }
    q[idx] = acc + attn_b[h];
}

// ---------------------------------------------------------------------------
// Energy MFMA GEMM + fused tanh/v/row-reduce (unchanged from round 2).
// M=16384 N=1024 K=1024. BM=BN=128, BK=32, 16x16x32 bf16.
// ---------------------------------------------------------------------------
__global__ __launch_bounds__(256) void k_energy_mfma(const short* __restrict__ encb,
                                                     const short* __restrict__ w2b,
                                                     const float* __restrict__ q,
                                                     const float* __restrict__ v,
                                                     float* __restrict__ part) {
    __shared__ __align__(16) short A_s[128 * 32];
    __shared__ __align__(16) short B_s[128 * 32];
    __shared__ float red[128][33];

    const int tid  = threadIdx.x;
    const int wave = tid >> 6, lane = tid & 63;
    const int wr = wave >> 1, wc = wave & 1;
    const int c16 = lane & 15, q4 = lane >> 4;
    const int m0 = blockIdx.x * 128;
    const int n0 = blockIdx.y * 128;

    f32x4 acc[4][4] = {};

    const int u0 = wave * 128 + lane;
    const int rowA0 = u0 >> 2,        rowA1 = (u0 + 64) >> 2;
    const int ofsA0 = (u0 & 3) * 8,   ofsA1 = ((u0 + 64) & 3) * 8;
    short* ldsA0 = A_s + wave * 1024;
    short* ldsA1 = A_s + wave * 1024 + 512;
    short* ldsB0 = B_s + wave * 1024;
    short* ldsB1 = B_s + wave * 1024 + 512;
    const short* gA = encb + (size_t)m0 * H;
    const short* gB = w2b + (size_t)n0 * H;

    for (int k0 = 0; k0 < H; k0 += 32) {
        __syncthreads();
        glds16(gA + (size_t)rowA0 * H + k0 + ofsA0, ldsA0);
        glds16(gA + (size_t)rowA1 * H + k0 + ofsA1, ldsA1);
        glds16(gB + (size_t)rowA0 * H + k0 + ofsA0, ldsB0);
        glds16(gB + (size_t)rowA1 * H + k0 + ofsA1, ldsB1);
        __syncthreads();

        short8 a[4], b[4];
#pragma unroll
        for (int i = 0; i < 4; i++)
            a[i] = *(const short8*)(A_s + (wr * 64 + i * 16 + c16) * 32 + q4 * 8);
#pragma unroll
        for (int j = 0; j < 4; j++)
            b[j] = *(const short8*)(B_s + (wc * 64 + j * 16 + c16) * 32 + q4 * 8);
#pragma unroll
        for (int i = 0; i < 4; i++)
#pragma unroll
            for (int j = 0; j < 4; j++)
                acc[i][j] = __builtin_amdgcn_mfma_f32_16x16x32_bf16(a[i], b[j], acc[i][j], 0, 0, 0);
    }

    const float* qb = q + (size_t)blockIdx.x * H;   // b == blockIdx.x (BM==S)
#pragma unroll
    for (int i = 0; i < 4; i++) {
#pragma unroll
        for (int r = 0; r < 4; r++) {
            float s = 0.f;
#pragma unroll
            for (int j = 0; j < 4; j++) {
                int n = n0 + wc * 64 + j * 16 + c16;
                s += v[n] * fast_tanh(qb[n] + acc[i][j][r]);
            }
            red[wr * 64 + i * 16 + q4 * 4 + r][wc * 16 + c16] = s;
        }
    }
    __syncthreads();
    if (tid < 128) {
        float s = 0.f;
#pragma unroll
        for (int c = 0; c < 32; c++) s += red[tid][c];
        part[(size_t)(m0 + tid) * 8 + blockIdx.y] = s;
    }
}

// ---------------------------------------------------------------------------
// Softmax over S + context, fused with xin packing:
// xin[b] = [bf16(emb[x[b]]) | bf16(ctx[b]) | bf16(h_last[b])]  (KG=2560 wide)
// One block per b, 256 threads.
// ---------------------------------------------------------------------------
__global__ __launch_bounds__(256) void k_softmax_ctx(const float* __restrict__ part,
                                                     const short* __restrict__ encb,
                                                     const int* __restrict__ x,
                                                     const float* __restrict__ emb,
                                                     const float* __restrict__ hlast,
                                                     float* __restrict__ attn_out,
                                                     short* __restrict__ xinb) {
    const int b = blockIdx.x;
    const int tid = threadIdx.x;
    __shared__ float w[S];
    __shared__ float red[128];

    float val = 0.f;
    if (tid < S) {
        const float* p = part + (size_t)(b * S + tid) * 8;
#pragma unroll
        for (int t = 0; t < 8; t++) val += p[t];
        w[tid] = val;
        red[tid] = val;
    }
    __syncthreads();
#pragma unroll
    for (int s = 64; s > 0; s >>= 1) {
        if (tid < s) red[tid] = fmaxf(red[tid], red[tid + s]);
        __syncthreads();
    }
    float m = red[0];
    __syncthreads();
    if (tid < S) { val = __expf(w[tid] - m); red[tid] = val; }
    __syncthreads();
#pragma unroll
    for (int s = 64; s > 0; s >>= 1) {
        if (tid < s) red[tid] += red[tid + s];
        __syncthreads();
    }
    float inv = 1.f / red[0];
    if (tid < S) {
        float ww = val * inv;
        w[tid] = ww;
        attn_out[b * S + tid] = ww;
    }
    // pack emb gather + h segments (independent of w)
    {
        int xv = x[b];
        float2 e2 = *(const float2*)(emb + (size_t)xv * E + tid * 2);
        short2 eo = { f2bf(e2.x), f2bf(e2.y) };
        *(short2*)(xinb + (size_t)b * KG + tid * 2) = eo;
        float4 h4 = *(const float4*)(hlast + (size_t)b * H + tid * 4);
        short4 ho = { f2bf(h4.x), f2bf(h4.y), f2bf(h4.z), f2bf(h4.w) };
        *(short4*)(xinb + (size_t)b * KG + KX + tid * 4) = ho;
    }
    __syncthreads();

    // context: 2 h per thread per pass, 2 passes (ushort2 loads)
    for (int hb = 0; hb < 2; hb++) {
        int h = hb * 512 + tid * 2;
        const unsigned short* e = (const unsigned short*)encb + (size_t)b * S * H + h;
        float a0 = 0.f, a1 = 0.f;
#pragma unroll 4
        for (int s = 0; s < S; s++) {
            unsigned u = *(const unsigned*)(e + (size_t)s * H);
            float ws_ = w[s];
            a0 += ws_ * bf2f((unsigned short)(u & 0xFFFFu));
            a1 += ws_ * bf2f((unsigned short)(u >> 16));
        }
        short2 o = { f2bf(a0), f2bf(a1) };
        *(short2*)(xinb + (size_t)b * KG + E + h) = o;
    }
}

// ---------------------------------------------------------------------------
// Gates MFMA GEMM: gates[m,n] = xin[m,:] @ [W_ih|W_hh][n,:] + b_ih[n] + b_hh[n]
// M=128, N=4096, K=2560. BM=128, BN=32, BK=32, grid 128, 256 thr.
// B converted fp32->bf16 inline with register prefetch. KX%32==0 so the
// W_ih/W_hh branch is uniform per k-iteration.
// ---------------------------------------------------------------------------
__global__ __launch_bounds__(256) void k_gates_mfma(const short* __restrict__ xinb,
                                                    const float* __restrict__ W_ih,
                                                    const float* __restrict__ W_hh,
                                                    const float* __restrict__ b_ih,
                                                    const float* __restrict__ b_hh,
                                                    float* __restrict__ gates) {
    __shared__ __align__(16) short A_s[128 * 32];
    __shared__ __align__(16) short B_s[32 * 32];

    const int tid  = threadIdx.x;
    const int wave = tid >> 6, lane = tid & 63;
    const int c16 = lane & 15, q4 = lane >> 4;
    const int n0 = blockIdx.x * 32;

    f32x4 acc[2][2] = {};

    // A staging (glds16): 512 units of 16B, wave handles [wave*128, +128)
    const int u0 = wave * 128 + lane;
    const int rowA0 = u0 >> 2,        rowA1 = (u0 + 64) >> 2;
    const int ofsA0 = (u0 & 3) * 8,   ofsA1 = ((u0 + 64) & 3) * 8;
    short* ldsA0 = A_s + wave * 1024;
    short* ldsA1 = A_s + wave * 1024 + 512;

    // B: 32 rows x 32 k fp32 = 256 float4 units; 1 per thread
    const int rB = tid >> 3;
    const int cB = (tid & 7) * 4;

    auto loadB = [&](int k0) -> float4 {
        if (k0 + cB < KX)
            return *(const float4*)(W_ih + (size_t)(n0 + rB) * KX + k0 + cB);
        else
            return *(const float4*)(W_hh + (size_t)(n0 + rB) * H + (k0 - KX) + cB);
    };
    float4 pb = loadB(0);

    for (int k0 = 0; k0 < KG; k0 += 32) {
        __syncthreads();
        short4 wv = { f2bf(pb.x), f2bf(pb.y), f2bf(pb.z), f2bf(pb.w) };
        *(short4*)(B_s + rB * 32 + cB) = wv;
        glds16(xinb + (size_t)rowA0 * KG + k0 + ofsA0, ldsA0);
        glds16(xinb + (size_t)rowA1 * KG + k0 + ofsA1, ldsA1);
        __syncthreads();
        if (k0 + 32 < KG) pb = loadB(k0 + 32);

        short8 a[2], bfr[2];
#pragma unroll
        for (int i = 0; i < 2; i++)
            a[i] = *(const short8*)(A_s + (wave * 32 + i * 16 + c16) * 32 + q4 * 8);
#pragma unroll
        for (int j = 0; j < 2; j++)
            bfr[j] = *(const short8*)(B_s + (j * 16 + c16) * 32 + q4 * 8);
#pragma unroll
        for (int i = 0; i < 2; i++)
#pragma unroll
            for (int j = 0; j < 2; j++)
                acc[i][j] = __builtin_amdgcn_mfma_f32_16x16x32_bf16(a[i], bfr[j], acc[i][j], 0, 0, 0);
    }

#pragma unroll
    for (int i = 0; i < 2; i++)
#pragma unroll
        for (int j = 0; j < 2; j++)
#pragma unroll
            for (int r = 0; r < 4; r++) {
                int R = wave * 32 + i * 16 + q4 * 4 + r;
                int n = n0 + j * 16 + c16;
                gates[(size_t)R * G4 + n] = acc[i][j][r] + b_ih[n] + b_hh[n];
            }
}

// ---------------------------------------------------------------------------
// LSTM pointwise; emits xout = [bf16(h_new) | bf16(ctx)] (ctx copied from xin,
// already rounded). Also fp32 h_new / c_new outputs.
// ---------------------------------------------------------------------------
__global__ __launch_bounds__(256) void k_lstm(const float* __restrict__ gates,
                                              const float* __restrict__ cell,
                                              const short* __restrict__ xinb,
                                              float* __restrict__ out_h,
                                              float* __restrict__ out_c,
                                              short* __restrict__ xoutb) {
    int idx = blockIdx.x * 256 + threadIdx.x;
    int b = idx >> 10;
    int h = idx & (H - 1);
    const float* g = gates + (size_t)b * G4;
    float ig = g[h], fg = g[H + h], gg = g[2 * H + h], og = g[3 * H + h];
    float si = 1.f / (1.f + expf(-ig));
    float sf = 1.f / (1.f + expf(-fg));
    float so = 1.f / (1.f + expf(-og));
    float c = sf * cell[idx] + si * tanhf(gg);
    float hn = so * tanhf(c);
    out_h[idx] = hn;
    out_c[idx] = c;
    xoutb[(size_t)b * H2 + h] = f2bf(hn);
    xoutb[(size_t)b * H2 + H + h] = xinb[(size_t)b * KG + E + h];
}

// ---------------------------------------------------------------------------
// fc MFMA GEMM: logits[m,n] = xoutb[m,:]@fc_W[n,:] + fc_b[n]
// M=128 N=32000 K=2048. BM=128, BN=64, BK=32; inline fp32->bf16 B with
// register prefetch. (unchanged from round 2)
// ---------------------------------------------------------------------------
__global__ __launch_bounds__(256) void k_fc_mfma(const short* __restrict__ xoutb,
                                                 const float* __restrict__ fcW,
                                                 const float* __restrict__ fcb,
                                                 float* __restrict__ logits) {
    __shared__ __align__(16) short A_s[128 * 32];
    __shared__ __align__(16) short B_s[64 * 32];

    const int tid  = threadIdx.x;
    const int wave = tid >> 6, lane = tid & 63;
    const int wr = wave >> 1, wc = wave & 1;
    const int c16 = lane & 15, q4 = lane >> 4;
    const int n0 = blockIdx.x * 64;

    f32x4 acc[4][2] = {};

    const int u0 = wave * 128 + lane;
    const int rowA0 = u0 >> 2,        rowA1 = (u0 + 64) >> 2;
    const int ofsA0 = (u0 & 3) * 8,   ofsA1 = ((u0 + 64) & 3) * 8;
    short* ldsA0 = A_s + wave * 1024;
    short* ldsA1 = A_s + wave * 1024 + 512;

    const int rB0 = tid >> 3,           rB1 = (tid + 256) >> 3;
    const int cB0 = (tid & 7) * 4;
    const float* gB0 = fcW + (size_t)(n0 + rB0) * H2 + cB0;
    const float* gB1 = fcW + (size_t)(n0 + rB1) * H2 + cB0;

    float4 pb0 = *(const float4*)(gB0);
    float4 pb1 = *(const float4*)(gB1);

    for (int kk = 0; kk < H2 / 32; kk++) {
        const int k0 = kk * 32;
        __syncthreads();
        short4 w0 = { f2bf(pb0.x), f2bf(pb0.y), f2bf(pb0.z), f2bf(pb0.w) };
        short4 w1 = { f2bf(pb1.x), f2bf(pb1.y), f2bf(pb1.z), f2bf(pb1.w) };
        *(short4*)(B_s + rB0 * 32 + cB0) = w0;
        *(short4*)(B_s + rB1 * 32 + cB0) = w1;
        glds16(xoutb + (size_t)rowA0 * H2 + k0 + ofsA0, ldsA0);
        glds16(xoutb + (size_t)rowA1 * H2 + k0 + ofsA1, ldsA1);
        __syncthreads();
        if (kk < H2 / 32 - 1) {
            pb0 = *(const float4*)(gB0 + k0 + 32);
            pb1 = *(const float4*)(gB1 + k0 + 32);
        }

        short8 a[4], b[2];
#pragma unroll
        for (int i = 0; i < 4; i++)
            a[i] = *(const short8*)(A_s + (wr * 64 + i * 16 + c16) * 32 + q4 * 8);
#pragma unroll
        for (int j = 0; j < 2; j++)
            b[j] = *(const short8*)(B_s + (wc * 32 + j * 16 + c16) * 32 + q4 * 8);
#pragma unroll
        for (int i = 0; i < 4; i++)
#pragma unroll
            for (int j = 0; j < 2; j++)
                acc[i][j] = __builtin_amdgcn_mfma_f32_16x16x32_bf16(a[i], b[j], acc[i][j], 0, 0, 0);
    }

#pragma unroll
    for (int i = 0; i < 4; i++)
#pragma unroll
        for (int j = 0; j < 2; j++)
#pragma unroll
            for (int r = 0; r < 4; r++) {
                int R = wr * 64 + i * 16 + q4 * 4 + r;
                int n = n0 + wc * 32 + j * 16 + c16;
                logits[(size_t)R * V + n] = acc[i][j][r] + fcb[n];
            }
}

// ---------------------------------------------------------------------------
extern "C" void kernel_launch(void* const* d_in, const int* in_sizes, int n_in,
                              void* d_out, int out_size, void* d_ws, size_t ws_size,
                              hipStream_t stream) {
    const int*   x      = (const int*)d_in[0];
    const float* hidden = (const float*)d_in[1];
    const float* cell   = (const float*)d_in[2];
    const float* enc    = (const float*)d_in[3];
    const float* emb    = (const float*)d_in[4];
    const float* attn_W = (const float*)d_in[5];
    const float* attn_b = (const float*)d_in[6];
    const float* v      = (const float*)d_in[7];
    const float* W_ih   = (const float*)d_in[8];
    const float* W_hh   = (const float*)d_in[9];
    const float* b_ih   = (const float*)d_in[10];
    const float* b_hh   = (const float*)d_in[11];
    const float* fc_W   = (const float*)d_in[12];
    const float* fc_b   = (const float*)d_in[13];

    float* out = (float*)d_out;
    float* logits   = out;                                   // [B,V]
    float* out_h    = out + (size_t)B * V;                   // [1,B,H]
    float* out_c    = out_h + (size_t)B * H;                 // [1,B,H]
    float* out_attn = out_c + (size_t)B * H;                 // [B,S]

    // workspace layout (16B-aligned)
    char* ws = (char*)d_ws;
    short* encb  = (short*)ws;   ws += (size_t)BS * H * 2;   // 33.5 MB
    short* w2b   = (short*)ws;   ws += (size_t)H * H * 2;    // 2 MB
    short* xinb  = (short*)ws;   ws += (size_t)B * KG * 2;   // 0.66 MB
    short* xoutb = (short*)ws;   ws += (size_t)B * H2 * 2;   // 0.5 MB
    float* q     = (float*)ws;   ws += (size_t)B * H * 4;
    float* part  = (float*)ws;   ws += (size_t)BS * 8 * 4;
    float* gates = (float*)ws;   ws += (size_t)B * G4 * 4;

    k_cvt<<<dim3(16384 + 1024), dim3(256), 0, stream>>>(enc, encb, attn_W, w2b);
    k_q<<<dim3(B * H / 256), dim3(256), 0, stream>>>(hidden, attn_W, attn_b, q);
    k_energy_mfma<<<dim3(BS / 128, H / 128), dim3(256), 0, stream>>>(encb, w2b, q, v, part);
    k_softmax_ctx<<<dim3(B), dim3(256), 0, stream>>>(part, encb, x, emb, hidden, out_attn, xinb);
    k_gates_mfma<<<dim3(G4 / 32), dim3(256), 0, stream>>>(xinb, W_ih, W_hh, b_ih, b_hh, gates);
    k_lstm<<<dim3(B * H / 256), dim3(256), 0, stream>>>(gates, cell, xinb, out_h, out_c, xoutb);
    k_fc_mfma<<<dim3(V / 64), dim3(256), 0, stream>>>(xoutb, fc_W, fc_b, logits);
}